// Round 10
// baseline (119.076 us; speedup 1.0000x reference)
//
#include <hip/hip_runtime.h>
#include <hip/hip_fp16.h>

// InnerProductDecoder2: fused edge gather + gumbel-argmax + sigmoid select.
// Round-10: round-9 structure (fp16 gather, 8-lane groups, wave-cooperative
// f64 borderline resolve) + NON-TEMPORAL hints on all streaming traffic:
//   - nt-store for out: kills the 25.6 MB write-allocate RFO fetch;
//   - nt-load for edge-index and gumbel streams: evict-first, protects the
//     L3-resident zh's L2 footprint (gather hit rate);
//   - cvt pass: nt-load z1 / nt-store zh (no RFO, no pollution).
// Rationale: measured line rate is ~23-26k 128B-lines/us across rounds 4..9
// regardless of structure -> random-gather line-rate ceiling; time scales
// with L2-miss lines, so cut lines. f64 resolve mirrors the float64 numpy
// reference -> the discrete flag never flips.

constexpr int D = 64;
#define TAU 0.05f

using half2v = _Float16 __attribute__((ext_vector_type(2)));

static __device__ __forceinline__ float2 h2f2(unsigned int u)
{
    return __half22float2(__builtin_bit_cast(__half2, u));
}

static __device__ __forceinline__ float fdot2f(unsigned int a, unsigned int b, float c)
{
#if __has_builtin(__builtin_amdgcn_fdot2)
    return __builtin_amdgcn_fdot2(__builtin_bit_cast(half2v, a),
                                  __builtin_bit_cast(half2v, b), c, false);
#else
    const float2 fa = h2f2(a), fb = h2f2(b);
    return c + fa.x * fb.x + fa.y * fb.y;
#endif
}

// nt float2 load via u64 bit_cast (float2 is a struct; builtin needs scalar)
static __device__ __forceinline__ float2 nt_load_f2(const float* p)
{
    unsigned long long u =
        __builtin_nontemporal_load((const unsigned long long*)p);
    return __builtin_bit_cast(float2, u);
}

// Detect whether edge_index was passed as int64 or int32.
__global__ void detect_i64_kernel(const void* __restrict__ eidx, long long nmax,
                                  int nsamp, int* __restrict__ flag)
{
    if (blockIdx.x == 0 && threadIdx.x == 0) {
        const long long* p = (const long long*)eidx;
        int ok = 1;
        for (int i = 0; i < nsamp; ++i) {
            long long v = p[i];
            if (v < 0 || v >= nmax) { ok = 0; break; }
        }
        *flag = ok;
    }
}

// f32 -> f16 conversion of z1 (4 elems per thread, fully coalesced, nt)
__global__ __launch_bounds__(256) void cvt_half_kernel(
    const float* __restrict__ z1, __half* __restrict__ zh, long long n4)
{
    long long i = (long long)blockIdx.x * blockDim.x + threadIdx.x;
    const long long stride = (long long)gridDim.x * blockDim.x;
    for (; i < n4; i += stride) {
        float4 v;
        v.x = __builtin_nontemporal_load(z1 + i * 4 + 0);
        v.y = __builtin_nontemporal_load(z1 + i * 4 + 1);
        v.z = __builtin_nontemporal_load(z1 + i * 4 + 2);
        v.w = __builtin_nontemporal_load(z1 + i * 4 + 3);
        __half2 h0 = __floats2half2_rn(v.x, v.y);
        __half2 h1 = __floats2half2_rn(v.z, v.w);
        unsigned long long o =
            ((unsigned long long)__builtin_bit_cast(unsigned int, h1) << 32) |
            __builtin_bit_cast(unsigned int, h0);
        __builtin_nontemporal_store(o, (unsigned long long*)(zh + i * 4));
    }
}

// exact f64 recompute of one edge (serial form; fallback kernel only)
static __device__ __forceinline__ void exact_edge(
    const float* __restrict__ z1, const float* __restrict__ gu,
    bool is64, bool tpos, const void* __restrict__ eidx, int E, long long e,
    float* sg_out, float* flag_out)
{
    long long s, d;
    if (is64) { s = ((const long long*)eidx)[e]; d = ((const long long*)eidx)[E + e]; }
    else      { s = ((const int*)eidx)[e];       d = ((const int*)eidx)[E + e]; }
    const float* ra = z1 + s * D;
    const float* rb = z1 + d * D;
    double acc = 0.0;
    for (int j = 2; j < D; ++j)
        acc += (double)ra[j] * (double)rb[j];
    const float2 uu = *(const float2*)(gu + 2 * e);
    const double w0 = fmin(fmax((double)uu.x, 1e-10), 1.0 - 1e-10);
    const double w1 = fmin(fmax((double)uu.y, 1e-10), 1.0 - 1e-10);
    const double G0 = -log(-log(w0));
    const double G1 = -log(-log(w1));
    const double N0 = acc + G0;
    const bool f2 = tpos ? (N0 >= G1) : (N0 <= G1);
    const double xx = f2 ? acc : ((double)ra[0] + (double)rb[0]);
    *sg_out   = (float)(1.0 / (1.0 + exp(-xx)));
    *flag_out = f2 ? 1.0f : 0.0f;
}

// ---------------- fp16-gather main kernel ----------------
__global__ __launch_bounds__(256, 4) void ipd2_h8_kernel(
    const float* __restrict__ z1,        // original f32 (borderline resolve)
    const __half* __restrict__ zh,       // fp16 copy (fast path)
    const float* __restrict__ gu,
    const int* __restrict__ temp_p,
    const void* __restrict__ eidx,
    float* __restrict__ out,
    int E,
    const int* __restrict__ i64flag)
{
    const bool is64 = (*i64flag != 0);
    const bool tpos = (*temp_p > 0);

    __shared__ float s_vf[4][64];
    __shared__ float s_vn[4][64];

    const int lane = threadIdx.x & 63;
    const int wid  = threadIdx.x >> 6;
    const int grp  = lane >> 3;              // 8-lane group (0..7)
    const int sub  = lane & 7;

    const long long wgid   = ((long long)blockIdx.x * blockDim.x + threadIdx.x) >> 6;
    const long long nwaves = ((long long)gridDim.x * blockDim.x) >> 6;
    const long long bstep  = nwaves * 64;

    const int*       p32 = (const int*)eidx;
    const long long* p64 = (const long long*)eidx;

    const long long base0 = wgid * 64;
    if (base0 >= E) return;

    // prologue: batch-0 indices + gumbel (clamped, nt streams)
    long long e0 = base0 + lane; if (e0 >= E) e0 = E - 1;
    int sj, dj;
    if (is64) {
        sj = (int)__builtin_nontemporal_load(&p64[e0]);
        dj = (int)__builtin_nontemporal_load(&p64[E + e0]);
    } else {
        sj = __builtin_nontemporal_load(&p32[e0]);
        dj = __builtin_nontemporal_load(&p32[E + e0]);
    }
    float2 uu = nt_load_f2(gu + 2 * e0);

    for (long long base = base0; base < E; base += bstep) {
        const long long eL  = base + lane;
        const bool      okL = eL < E;

        // prefetch NEXT batch's indices + gumbel (branchless, clamped, nt)
        long long eN = base + bstep + lane;
        if (eN >= E) eN = E - 1;
        int nsj, ndj;
        if (is64) {
            nsj = (int)__builtin_nontemporal_load(&p64[eN]);
            ndj = (int)__builtin_nontemporal_load(&p64[E + eN]);
        } else {
            nsj = __builtin_nontemporal_load(&p32[eN]);
            ndj = __builtin_nontemporal_load(&p32[E + eN]);
        }
        const float2 nuu = nt_load_f2(gu + 2 * eN);

        // tail VALU hoisted over gather latency
        const float u0 = fminf(fmaxf(uu.x, 1e-10f), 0.99999994f);
        const float u1 = fminf(fmaxf(uu.y, 1e-10f), 0.99999994f);
        const float g0 = -logf(-logf(u0));
        const float g1 = -logf(-logf(u1));

        // ---- phase 1: dots; group g owns edges base+g*8..base+g*8+7.
        // Two half-batches of 4 edges/group: uint4 a[4],b[4] = 32 VGPRs live
        // (NOT 64 -> no spill; round-6 lesson). zh gathers stay CACHED loads.
        if (base + 64 <= E) {
            #pragma unroll
            for (int half = 0; half < 2; ++half) {
                uint4 a[4], b[4];
                #pragma unroll
                for (int k = 0; k < 4; ++k) {
                    const int sl = grp * 8 + half * 4 + k;  // owner lane
                    const int s  = __shfl(sj, sl, 64);
                    const int d  = __shfl(dj, sl, 64);
                    a[k] = *(const uint4*)(zh + (size_t)s * D + sub * 8);
                    b[k] = *(const uint4*)(zh + (size_t)d * D + sub * 8);
                }
                #pragma unroll
                for (int k = 0; k < 4; ++k) {
                    // lane covers halfs [8*sub, 8*sub+8); a.x = cols {8s,8s+1}
                    const float t0 = fdot2f(a[k].x, b[k].x, 0.0f);
                    float acc = (sub == 0) ? 0.0f : t0;   // exclude cols 0,1
                    acc = fdot2f(a[k].y, b[k].y, acc);
                    acc = fdot2f(a[k].z, b[k].z, acc);
                    acc = fdot2f(a[k].w, b[k].w, acc);
                    #pragma unroll
                    for (int m = 1; m < 8; m <<= 1)
                        acc += __shfl_xor(acc, m, 64);    // within 8-lane group
                    if (sub == 0) {
                        s_vf[wid][grp * 8 + half * 4 + k] = acc;
                        s_vn[wid][grp * 8 + half * 4 + k] =
                            h2f2(a[k].x).x + h2f2(b[k].x).x;   // col0 + col0
                    }
                }
            }
        } else {
            // generic tail batch (only when 64 does not divide E)
            for (int it = 0; it < 8; ++it) {
                const long long e = base + grp * 8 + it;
                const int s = __shfl(sj, grp * 8 + it, 64);
                const int d = __shfl(dj, grp * 8 + it, 64);
                if (e < E) {
                    const uint4 a = *(const uint4*)(zh + (size_t)s * D + sub * 8);
                    const uint4 b = *(const uint4*)(zh + (size_t)d * D + sub * 8);
                    const float t0 = fdot2f(a.x, b.x, 0.0f);
                    float acc = (sub == 0) ? 0.0f : t0;
                    acc = fdot2f(a.y, b.y, acc);
                    acc = fdot2f(a.z, b.z, acc);
                    acc = fdot2f(a.w, b.w, acc);
                    #pragma unroll
                    for (int m = 1; m < 8; m <<= 1)
                        acc += __shfl_xor(acc, m, 64);
                    if (sub == 0) {
                        s_vf[wid][grp * 8 + it] = acc;
                        s_vn[wid][grp * 8 + it] = h2f2(a.x).x + h2f2(b.x).x;
                    }
                }
            }
        }

        // ---- phase 2: tails, lane j -> edge base+j ----
        bool border = false;
        if (okL) {
            const float vf = s_vf[wid][lane];
            const float vn = s_vn[wid][lane];

            const float n0 = vf + g0;
            // argmax(softmax((la+g)/t)) monotone in la+g for t>0, reversed t<0;
            // tie -> index 0 -> flag = 1.
            const bool  flag  = tpos ? (n0 >= g1) : (n0 <= g1);
            const float x     = flag ? vf : vn;

            border = fabsf(n0 - g1) < TAU;
            if (!border) {
                __builtin_nontemporal_store(1.0f / (1.0f + expf(-x)), &out[eL]);
                __builtin_nontemporal_store(flag ? 1.0f : 0.0f, &out[E + eL]);
            }
        }

        // ---- wave-cooperative borderline resolve (exact f64) ----
        unsigned long long mask = __ballot(border);
        while (mask) {
            const int b = (int)(__ffsll((long long)mask) - 1);
            mask &= mask - 1;

            const int s = __shfl(sj, b, 64);
            const int d = __shfl(dj, b, 64);
            // full wave loads both rows coalesced: 1 dword/lane each
            const float av = z1[(size_t)s * D + lane];
            const float bv = z1[(size_t)d * D + lane];

            double prod = (lane >= 2) ? (double)av * (double)bv : 0.0;
            #pragma unroll
            for (int m = 1; m < 64; m <<= 1)
                prod += __shfl_xor(prod, m, 64);         // full-wave f64 sum
            const double vnd = __shfl((double)av + (double)bv, 0, 64);

            const float ux = __shfl(uu.x, b, 64);
            const float uy = __shfl(uu.y, b, 64);

            // f64 gumbel chain computed redundantly on all lanes (uniform)
            const double w0 = fmin(fmax((double)ux, 1e-10), 1.0 - 1e-10);
            const double w1 = fmin(fmax((double)uy, 1e-10), 1.0 - 1e-10);
            const double G0 = -log(-log(w0));
            const double G1 = -log(-log(w1));
            const double N0 = prod + G0;
            const bool f2 = tpos ? (N0 >= G1) : (N0 <= G1);
            const double xx = f2 ? prod : vnd;

            if (lane == 0) {
                const long long eb = base + b;
                __builtin_nontemporal_store(
                    (float)(1.0 / (1.0 + exp(-xx))), &out[eb]);
                __builtin_nontemporal_store(f2 ? 1.0f : 0.0f, &out[E + eb]);
            }
        }

        sj = nsj; dj = ndj; uu = nuu;
    }
}

// ---------------- f32 fallback (round-4 proven kernel) for tiny ws ----------------
__global__ __launch_bounds__(256, 4) void ipd2_f32_kernel(
    const float* __restrict__ z1,
    const float* __restrict__ gu,
    const int* __restrict__ temp_p,
    const void* __restrict__ eidx,
    float* __restrict__ out,
    int E,
    const int* __restrict__ i64flag)
{
    const bool is64 = (*i64flag != 0);
    const bool tpos = (*temp_p > 0);

    __shared__ float s_vf[4][64];
    __shared__ float s_vn[4][64];

    const int lane = threadIdx.x & 63;
    const int wid  = threadIdx.x >> 6;
    const int grp  = lane >> 4;
    const int sub  = lane & 15;

    const long long wgid   = ((long long)blockIdx.x * blockDim.x + threadIdx.x) >> 6;
    const long long nwaves = ((long long)gridDim.x * blockDim.x) >> 6;
    const long long bstep  = nwaves * 64;

    const int*       p32 = (const int*)eidx;
    const long long* p64 = (const long long*)eidx;

    const long long base0 = wgid * 64;
    if (base0 >= E) return;

    long long e0 = base0 + lane; if (e0 >= E) e0 = E - 1;
    int sj, dj;
    if (is64) { sj = (int)p64[e0]; dj = (int)p64[E + e0]; }
    else      { sj = p32[e0];      dj = p32[E + e0]; }
    float2 uu = *(const float2*)(gu + 2 * e0);

    for (long long base = base0; base < E; base += bstep) {
        const long long eL  = base + lane;
        const bool      okL = eL < E;

        long long eN = base + bstep + lane;
        if (eN >= E) eN = E - 1;
        int nsj, ndj;
        if (is64) { nsj = (int)p64[eN]; ndj = (int)p64[E + eN]; }
        else      { nsj = p32[eN];      ndj = p32[E + eN]; }
        const float2 nuu = *(const float2*)(gu + 2 * eN);

        const float u0 = fminf(fmaxf(uu.x, 1e-10f), 0.99999994f);
        const float u1 = fminf(fmaxf(uu.y, 1e-10f), 0.99999994f);
        const float g0 = -logf(-logf(u0));
        const float g1 = -logf(-logf(u1));

        for (int it0 = 0; it0 < 16; it0 += 4) {
            float4 a[4], b[4];
            #pragma unroll
            for (int k = 0; k < 4; ++k) {
                const int sl = grp * 16 + it0 + k;
                const int s  = __shfl(sj, sl, 64);
                const int d  = __shfl(dj, sl, 64);
                long long e = base + sl;
                const size_t so   = (e < E) ? (size_t)s * D : 0;
                const size_t dofs = (e < E) ? (size_t)d * D : 0;
                a[k] = *(const float4*)(z1 + so + sub * 4);
                b[k] = *(const float4*)(z1 + dofs + sub * 4);
            }
            #pragma unroll
            for (int k = 0; k < 4; ++k) {
                float loc = a[k].z * b[k].z + a[k].w * b[k].w;
                if (sub != 0) loc += a[k].x * b[k].x + a[k].y * b[k].y;
                #pragma unroll
                for (int m = 1; m < 16; m <<= 1)
                    loc += __shfl_xor(loc, m, 64);
                if (sub == 0) {
                    s_vf[wid][grp * 16 + it0 + k] = loc;
                    s_vn[wid][grp * 16 + it0 + k] = a[k].x + b[k].x;
                }
            }
        }

        if (okL) {
            const float vf = s_vf[wid][lane];
            const float vn = s_vn[wid][lane];
            const float n0 = vf + g0;
            bool  flag  = tpos ? (n0 >= g1) : (n0 <= g1);
            float x     = flag ? vf : vn;
            float sg    = 1.0f / (1.0f + expf(-x));
            float oflag = flag ? 1.0f : 0.0f;

            if (fabsf(n0 - g1) < 0.004f) {
                exact_edge(z1, gu, is64, tpos, eidx, E, eL, &sg, &oflag);
            }

            out[eL]     = sg;
            out[E + eL] = oflag;
        }

        sj = nsj; dj = ndj; uu = nuu;
    }
}

extern "C" void kernel_launch(void* const* d_in, const int* in_sizes, int n_in,
                              void* d_out, int out_size, void* d_ws, size_t ws_size,
                              hipStream_t stream)
{
    const float* z1     = (const float*)d_in[0];
    const float* gu     = (const float*)d_in[1];
    const int*   temp_p = (const int*)d_in[2];
    const void*  eidx   = d_in[3];
    float*       out    = (float*)d_out;

    const int E = in_sizes[1] / 2;          // gumbel_u is (E,2)
    const long long N = in_sizes[0] / D;    // z1 is (N,64)

    int* i64flag = (int*)d_ws;
    const size_t zh_bytes = (size_t)N * D * sizeof(__half);
    const size_t need     = 4096 + zh_bytes;

    detect_i64_kernel<<<1, 64, 0, stream>>>(eidx, N, 128, i64flag);

    if (ws_size >= need) {
        __half* zh = (__half*)((char*)d_ws + 4096);
        cvt_half_kernel<<<2048, 256, 0, stream>>>(z1, zh, (long long)N * D / 4);
        ipd2_h8_kernel<<<4096, 256, 0, stream>>>(
            z1, zh, gu, temp_p, eidx, out, E, i64flag);
    } else {
        ipd2_f32_kernel<<<4096, 256, 0, stream>>>(
            z1, gu, temp_p, eidx, out, E, i64flag);
    }
}

// Round 11
// 114.118 us; speedup vs baseline: 1.0434x; 1.0434x over previous
//
#include <hip/hip_runtime.h>
#include <hip/hip_fp16.h>

// InnerProductDecoder2: fused edge gather + gumbel-argmax + sigmoid select.
// Round-11 (polish): main kernel identical to round-10 (103.8 us measured:
// fp16 gather, 8-lane groups, fdot2, wave-cooperative f64 borderline resolve,
// nt-stores for out / nt-loads for idx+gumbel streams). Reverted the cvt
// kernel to the vectorized round-9 form (round-10's scalar nt loads
// un-vectorized it, costing ~4 us of the total) and parallelized the
// int64/int32 index-width detector across 64 lanes.
// Traffic accounting (measured): ~51-64 MB compulsory streams + ~240 MB
// structural zh capacity misses (12.8 MB working set vs 4 MB per-XCD L2) at
// the ~23k lines/us random-gather service ceiling -> main kernel is at its
// structural floor. f64 borderline resolve mirrors the float64 numpy
// reference -> the discrete flag never flips.

constexpr int D = 64;
#define TAU 0.05f

using half2v = _Float16 __attribute__((ext_vector_type(2)));

static __device__ __forceinline__ float2 h2f2(unsigned int u)
{
    return __half22float2(__builtin_bit_cast(__half2, u));
}

static __device__ __forceinline__ float fdot2f(unsigned int a, unsigned int b, float c)
{
#if __has_builtin(__builtin_amdgcn_fdot2)
    return __builtin_amdgcn_fdot2(__builtin_bit_cast(half2v, a),
                                  __builtin_bit_cast(half2v, b), c, false);
#else
    const float2 fa = h2f2(a), fb = h2f2(b);
    return c + fa.x * fb.x + fa.y * fb.y;
#endif
}

// nt float2 load via u64 bit_cast (float2 is a struct; builtin needs scalar)
static __device__ __forceinline__ float2 nt_load_f2(const float* p)
{
    unsigned long long u =
        __builtin_nontemporal_load((const unsigned long long*)p);
    return __builtin_bit_cast(float2, u);
}

// Detect whether edge_index was passed as int64 or int32 (wave-parallel).
// int32 data read as int64 pairs two indices: in-range requires the upper
// word == 0 (P ~ 1e-5 per sample) -> P(false-64 over 128 samples) ~ 1e-640.
__global__ void detect_i64_kernel(const void* __restrict__ eidx, long long nmax,
                                  int* __restrict__ flag)
{
    const int lane = threadIdx.x & 63;
    const long long* p = (const long long*)eidx;
    const long long v0 = p[lane];
    const long long v1 = p[64 + lane];
    const bool ok = (v0 >= 0) && (v0 < nmax) && (v1 >= 0) && (v1 < nmax);
    const bool all_ok = __all(ok);
    if (lane == 0) *flag = all_ok ? 1 : 0;
}

// f32 -> f16 conversion of z1 (4 elems per thread, fully coalesced)
__global__ __launch_bounds__(256) void cvt_half_kernel(
    const float* __restrict__ z1, __half* __restrict__ zh, long long n4)
{
    long long i = (long long)blockIdx.x * blockDim.x + threadIdx.x;
    const long long stride = (long long)gridDim.x * blockDim.x;
    for (; i < n4; i += stride) {
        const float4 v = *(const float4*)(z1 + i * 4);
        __half2 h0 = __floats2half2_rn(v.x, v.y);
        __half2 h1 = __floats2half2_rn(v.z, v.w);
        uint2 o;
        o.x = __builtin_bit_cast(unsigned int, h0);
        o.y = __builtin_bit_cast(unsigned int, h1);
        *(uint2*)(zh + i * 4) = o;
    }
}

// exact f64 recompute of one edge (serial form; fallback kernel only)
static __device__ __forceinline__ void exact_edge(
    const float* __restrict__ z1, const float* __restrict__ gu,
    bool is64, bool tpos, const void* __restrict__ eidx, int E, long long e,
    float* sg_out, float* flag_out)
{
    long long s, d;
    if (is64) { s = ((const long long*)eidx)[e]; d = ((const long long*)eidx)[E + e]; }
    else      { s = ((const int*)eidx)[e];       d = ((const int*)eidx)[E + e]; }
    const float* ra = z1 + s * D;
    const float* rb = z1 + d * D;
    double acc = 0.0;
    for (int j = 2; j < D; ++j)
        acc += (double)ra[j] * (double)rb[j];
    const float2 uu = *(const float2*)(gu + 2 * e);
    const double w0 = fmin(fmax((double)uu.x, 1e-10), 1.0 - 1e-10);
    const double w1 = fmin(fmax((double)uu.y, 1e-10), 1.0 - 1e-10);
    const double G0 = -log(-log(w0));
    const double G1 = -log(-log(w1));
    const double N0 = acc + G0;
    const bool f2 = tpos ? (N0 >= G1) : (N0 <= G1);
    const double xx = f2 ? acc : ((double)ra[0] + (double)rb[0]);
    *sg_out   = (float)(1.0 / (1.0 + exp(-xx)));
    *flag_out = f2 ? 1.0f : 0.0f;
}

// ---------------- fp16-gather main kernel (round-10, unchanged) ----------------
__global__ __launch_bounds__(256, 4) void ipd2_h8_kernel(
    const float* __restrict__ z1,        // original f32 (borderline resolve)
    const __half* __restrict__ zh,       // fp16 copy (fast path)
    const float* __restrict__ gu,
    const int* __restrict__ temp_p,
    const void* __restrict__ eidx,
    float* __restrict__ out,
    int E,
    const int* __restrict__ i64flag)
{
    const bool is64 = (*i64flag != 0);
    const bool tpos = (*temp_p > 0);

    __shared__ float s_vf[4][64];
    __shared__ float s_vn[4][64];

    const int lane = threadIdx.x & 63;
    const int wid  = threadIdx.x >> 6;
    const int grp  = lane >> 3;              // 8-lane group (0..7)
    const int sub  = lane & 7;

    const long long wgid   = ((long long)blockIdx.x * blockDim.x + threadIdx.x) >> 6;
    const long long nwaves = ((long long)gridDim.x * blockDim.x) >> 6;
    const long long bstep  = nwaves * 64;

    const int*       p32 = (const int*)eidx;
    const long long* p64 = (const long long*)eidx;

    const long long base0 = wgid * 64;
    if (base0 >= E) return;

    // prologue: batch-0 indices + gumbel (clamped, nt streams)
    long long e0 = base0 + lane; if (e0 >= E) e0 = E - 1;
    int sj, dj;
    if (is64) {
        sj = (int)__builtin_nontemporal_load(&p64[e0]);
        dj = (int)__builtin_nontemporal_load(&p64[E + e0]);
    } else {
        sj = __builtin_nontemporal_load(&p32[e0]);
        dj = __builtin_nontemporal_load(&p32[E + e0]);
    }
    float2 uu = nt_load_f2(gu + 2 * e0);

    for (long long base = base0; base < E; base += bstep) {
        const long long eL  = base + lane;
        const bool      okL = eL < E;

        // prefetch NEXT batch's indices + gumbel (branchless, clamped, nt)
        long long eN = base + bstep + lane;
        if (eN >= E) eN = E - 1;
        int nsj, ndj;
        if (is64) {
            nsj = (int)__builtin_nontemporal_load(&p64[eN]);
            ndj = (int)__builtin_nontemporal_load(&p64[E + eN]);
        } else {
            nsj = __builtin_nontemporal_load(&p32[eN]);
            ndj = __builtin_nontemporal_load(&p32[E + eN]);
        }
        const float2 nuu = nt_load_f2(gu + 2 * eN);

        // tail VALU hoisted over gather latency
        const float u0 = fminf(fmaxf(uu.x, 1e-10f), 0.99999994f);
        const float u1 = fminf(fmaxf(uu.y, 1e-10f), 0.99999994f);
        const float g0 = -logf(-logf(u0));
        const float g1 = -logf(-logf(u1));

        // ---- phase 1: dots; group g owns edges base+g*8..base+g*8+7.
        // Two half-batches of 4 edges/group: uint4 a[4],b[4] = 32 VGPRs live
        // (NOT 64 -> no spill; round-6 lesson). zh gathers stay CACHED loads.
        if (base + 64 <= E) {
            #pragma unroll
            for (int half = 0; half < 2; ++half) {
                uint4 a[4], b[4];
                #pragma unroll
                for (int k = 0; k < 4; ++k) {
                    const int sl = grp * 8 + half * 4 + k;  // owner lane
                    const int s  = __shfl(sj, sl, 64);
                    const int d  = __shfl(dj, sl, 64);
                    a[k] = *(const uint4*)(zh + (size_t)s * D + sub * 8);
                    b[k] = *(const uint4*)(zh + (size_t)d * D + sub * 8);
                }
                #pragma unroll
                for (int k = 0; k < 4; ++k) {
                    // lane covers halfs [8*sub, 8*sub+8); a.x = cols {8s,8s+1}
                    const float t0 = fdot2f(a[k].x, b[k].x, 0.0f);
                    float acc = (sub == 0) ? 0.0f : t0;   // exclude cols 0,1
                    acc = fdot2f(a[k].y, b[k].y, acc);
                    acc = fdot2f(a[k].z, b[k].z, acc);
                    acc = fdot2f(a[k].w, b[k].w, acc);
                    #pragma unroll
                    for (int m = 1; m < 8; m <<= 1)
                        acc += __shfl_xor(acc, m, 64);    // within 8-lane group
                    if (sub == 0) {
                        s_vf[wid][grp * 8 + half * 4 + k] = acc;
                        s_vn[wid][grp * 8 + half * 4 + k] =
                            h2f2(a[k].x).x + h2f2(b[k].x).x;   // col0 + col0
                    }
                }
            }
        } else {
            // generic tail batch (only when 64 does not divide E)
            for (int it = 0; it < 8; ++it) {
                const long long e = base + grp * 8 + it;
                const int s = __shfl(sj, grp * 8 + it, 64);
                const int d = __shfl(dj, grp * 8 + it, 64);
                if (e < E) {
                    const uint4 a = *(const uint4*)(zh + (size_t)s * D + sub * 8);
                    const uint4 b = *(const uint4*)(zh + (size_t)d * D + sub * 8);
                    const float t0 = fdot2f(a.x, b.x, 0.0f);
                    float acc = (sub == 0) ? 0.0f : t0;
                    acc = fdot2f(a.y, b.y, acc);
                    acc = fdot2f(a.z, b.z, acc);
                    acc = fdot2f(a.w, b.w, acc);
                    #pragma unroll
                    for (int m = 1; m < 8; m <<= 1)
                        acc += __shfl_xor(acc, m, 64);
                    if (sub == 0) {
                        s_vf[wid][grp * 8 + it] = acc;
                        s_vn[wid][grp * 8 + it] = h2f2(a.x).x + h2f2(b.x).x;
                    }
                }
            }
        }

        // ---- phase 2: tails, lane j -> edge base+j ----
        bool border = false;
        if (okL) {
            const float vf = s_vf[wid][lane];
            const float vn = s_vn[wid][lane];

            const float n0 = vf + g0;
            // argmax(softmax((la+g)/t)) monotone in la+g for t>0, reversed t<0;
            // tie -> index 0 -> flag = 1.
            const bool  flag  = tpos ? (n0 >= g1) : (n0 <= g1);
            const float x     = flag ? vf : vn;

            border = fabsf(n0 - g1) < TAU;
            if (!border) {
                __builtin_nontemporal_store(1.0f / (1.0f + expf(-x)), &out[eL]);
                __builtin_nontemporal_store(flag ? 1.0f : 0.0f, &out[E + eL]);
            }
        }

        // ---- wave-cooperative borderline resolve (exact f64) ----
        unsigned long long mask = __ballot(border);
        while (mask) {
            const int b = (int)(__ffsll((long long)mask) - 1);
            mask &= mask - 1;

            const int s = __shfl(sj, b, 64);
            const int d = __shfl(dj, b, 64);
            // full wave loads both rows coalesced: 1 dword/lane each
            const float av = z1[(size_t)s * D + lane];
            const float bv = z1[(size_t)d * D + lane];

            double prod = (lane >= 2) ? (double)av * (double)bv : 0.0;
            #pragma unroll
            for (int m = 1; m < 64; m <<= 1)
                prod += __shfl_xor(prod, m, 64);         // full-wave f64 sum
            const double vnd = __shfl((double)av + (double)bv, 0, 64);

            const float ux = __shfl(uu.x, b, 64);
            const float uy = __shfl(uu.y, b, 64);

            // f64 gumbel chain computed redundantly on all lanes (uniform)
            const double w0 = fmin(fmax((double)ux, 1e-10), 1.0 - 1e-10);
            const double w1 = fmin(fmax((double)uy, 1e-10), 1.0 - 1e-10);
            const double G0 = -log(-log(w0));
            const double G1 = -log(-log(w1));
            const double N0 = prod + G0;
            const bool f2 = tpos ? (N0 >= G1) : (N0 <= G1);
            const double xx = f2 ? prod : vnd;

            if (lane == 0) {
                const long long eb = base + b;
                __builtin_nontemporal_store(
                    (float)(1.0 / (1.0 + exp(-xx))), &out[eb]);
                __builtin_nontemporal_store(f2 ? 1.0f : 0.0f, &out[E + eb]);
            }
        }

        sj = nsj; dj = ndj; uu = nuu;
    }
}

// ---------------- f32 fallback (round-4 proven kernel) for tiny ws ----------------
__global__ __launch_bounds__(256, 4) void ipd2_f32_kernel(
    const float* __restrict__ z1,
    const float* __restrict__ gu,
    const int* __restrict__ temp_p,
    const void* __restrict__ eidx,
    float* __restrict__ out,
    int E,
    const int* __restrict__ i64flag)
{
    const bool is64 = (*i64flag != 0);
    const bool tpos = (*temp_p > 0);

    __shared__ float s_vf[4][64];
    __shared__ float s_vn[4][64];

    const int lane = threadIdx.x & 63;
    const int wid  = threadIdx.x >> 6;
    const int grp  = lane >> 4;
    const int sub  = lane & 15;

    const long long wgid   = ((long long)blockIdx.x * blockDim.x + threadIdx.x) >> 6;
    const long long nwaves = ((long long)gridDim.x * blockDim.x) >> 6;
    const long long bstep  = nwaves * 64;

    const int*       p32 = (const int*)eidx;
    const long long* p64 = (const long long*)eidx;

    const long long base0 = wgid * 64;
    if (base0 >= E) return;

    long long e0 = base0 + lane; if (e0 >= E) e0 = E - 1;
    int sj, dj;
    if (is64) { sj = (int)p64[e0]; dj = (int)p64[E + e0]; }
    else      { sj = p32[e0];      dj = p32[E + e0]; }
    float2 uu = *(const float2*)(gu + 2 * e0);

    for (long long base = base0; base < E; base += bstep) {
        const long long eL  = base + lane;
        const bool      okL = eL < E;

        long long eN = base + bstep + lane;
        if (eN >= E) eN = E - 1;
        int nsj, ndj;
        if (is64) { nsj = (int)p64[eN]; ndj = (int)p64[E + eN]; }
        else      { nsj = p32[eN];      ndj = p32[E + eN]; }
        const float2 nuu = *(const float2*)(gu + 2 * eN);

        const float u0 = fminf(fmaxf(uu.x, 1e-10f), 0.99999994f);
        const float u1 = fminf(fmaxf(uu.y, 1e-10f), 0.99999994f);
        const float g0 = -logf(-logf(u0));
        const float g1 = -logf(-logf(u1));

        for (int it0 = 0; it0 < 16; it0 += 4) {
            float4 a[4], b[4];
            #pragma unroll
            for (int k = 0; k < 4; ++k) {
                const int sl = grp * 16 + it0 + k;
                const int s  = __shfl(sj, sl, 64);
                const int d  = __shfl(dj, sl, 64);
                long long e = base + sl;
                const size_t so   = (e < E) ? (size_t)s * D : 0;
                const size_t dofs = (e < E) ? (size_t)d * D : 0;
                a[k] = *(const float4*)(z1 + so + sub * 4);
                b[k] = *(const float4*)(z1 + dofs + sub * 4);
            }
            #pragma unroll
            for (int k = 0; k < 4; ++k) {
                float loc = a[k].z * b[k].z + a[k].w * b[k].w;
                if (sub != 0) loc += a[k].x * b[k].x + a[k].y * b[k].y;
                #pragma unroll
                for (int m = 1; m < 16; m <<= 1)
                    loc += __shfl_xor(loc, m, 64);
                if (sub == 0) {
                    s_vf[wid][grp * 16 + it0 + k] = loc;
                    s_vn[wid][grp * 16 + it0 + k] = a[k].x + b[k].x;
                }
            }
        }

        if (okL) {
            const float vf = s_vf[wid][lane];
            const float vn = s_vn[wid][lane];
            const float n0 = vf + g0;
            bool  flag  = tpos ? (n0 >= g1) : (n0 <= g1);
            float x     = flag ? vf : vn;
            float sg    = 1.0f / (1.0f + expf(-x));
            float oflag = flag ? 1.0f : 0.0f;

            if (fabsf(n0 - g1) < 0.004f) {
                exact_edge(z1, gu, is64, tpos, eidx, E, eL, &sg, &oflag);
            }

            out[eL]     = sg;
            out[E + eL] = oflag;
        }

        sj = nsj; dj = ndj; uu = nuu;
    }
}

extern "C" void kernel_launch(void* const* d_in, const int* in_sizes, int n_in,
                              void* d_out, int out_size, void* d_ws, size_t ws_size,
                              hipStream_t stream)
{
    const float* z1     = (const float*)d_in[0];
    const float* gu     = (const float*)d_in[1];
    const int*   temp_p = (const int*)d_in[2];
    const void*  eidx   = d_in[3];
    float*       out    = (float*)d_out;

    const int E = in_sizes[1] / 2;          // gumbel_u is (E,2)
    const long long N = in_sizes[0] / D;    // z1 is (N,64)

    int* i64flag = (int*)d_ws;
    const size_t zh_bytes = (size_t)N * D * sizeof(__half);
    const size_t need     = 4096 + zh_bytes;

    detect_i64_kernel<<<1, 64, 0, stream>>>(eidx, N, i64flag);

    if (ws_size >= need) {
        __half* zh = (__half*)((char*)d_ws + 4096);
        cvt_half_kernel<<<2048, 256, 0, stream>>>(z1, zh, (long long)N * D / 4);
        ipd2_h8_kernel<<<4096, 256, 0, stream>>>(
            z1, zh, gu, temp_p, eidx, out, E, i64flag);
    } else {
        ipd2_f32_kernel<<<4096, 256, 0, stream>>>(
            z1, gu, temp_p, eidx, out, E, i64flag);
    }
}